// Round 14
// baseline (58.925 us; speedup 1.0000x reference)
//
#include <hip/hip_runtime.h>
#include <hip/hip_fp16.h>
#include <stdint.h>

#define THREADS 256
typedef float v2f __attribute__((ext_vector_type(2)));

// tanh(x) = 1 - 2/(exp(2x)+1) on an f32 pair (R7's form — best so far)
__device__ __forceinline__ v2f tanh2(v2f x) {
    v2f xs = x * 2.885390081777927f;                // 2*log2(e)
    v2f e  = { __builtin_amdgcn_exp2f(xs.x),
               __builtin_amdgcn_exp2f(xs.y) };
    v2f ep = e + 1.0f;
    v2f r  = { __builtin_amdgcn_rcpf(ep.x),
               __builtin_amdgcn_rcpf(ep.y) };
    return (v2f){-2.0f, -2.0f} * r + 1.0f;
}

// v_dot2_f32_f16: 2 f16 FMAs per issue slot, f32 accumulate
__device__ __forceinline__ float fdot2u(uint32_t a, uint32_t b, float c) {
#if __has_builtin(__builtin_amdgcn_fdot2)
    typedef _Float16 h2 __attribute__((ext_vector_type(2)));
    return __builtin_amdgcn_fdot2(__builtin_bit_cast(h2, a),
                                  __builtin_bit_cast(h2, b), c, false);
#else
    __half2 ha = __builtin_bit_cast(__half2, a), hb = __builtin_bit_cast(__half2, b);
    return c + __half2float(ha.x) * __half2float(hb.x)
             + __half2float(ha.y) * __half2float(hb.y);
#endif
}

// Dense via f16 dot2. Weights pre-packed (setup kernel) as K-pairs per output:
// wq[j*(IN/2)+p] = half2(W[2p][j], W[2p+1][j]) — uniform u32 s_loads.
// Packed x kept in a scalar uint32_t array (float/int scalar arrays promote to
// VGPRs; vector-typed arrays demoted to scratch in R10/R11 — avoid).
template<int IN, int OUT>
__device__ __forceinline__ void dense_h(const float* x, float* y,
                                        const uint32_t* __restrict__ wq,
                                        const float* __restrict__ b) {
    uint32_t hx[IN / 2];
#pragma unroll
    for (int p = 0; p < IN / 2; ++p)
        hx[p] = __builtin_bit_cast(uint32_t, __floats2half2_rn(x[2 * p], x[2 * p + 1]));
#pragma unroll
    for (int j = 0; j < OUT; j += 2) {
        float a0 = b[j], a1 = b[j + 1];
#pragma unroll
        for (int p = 0; p < IN / 2; ++p) {
            a0 = fdot2u(hx[p], wq[j * (IN / 2) + p], a0);
            a1 = fdot2u(hx[p], wq[(j + 1) * (IN / 2) + p], a1);
        }
        v2f t = tanh2((v2f){a0, a1});
        y[j] = t.x; y[j + 1] = t.y;
    }
}

// Pack all 6 layers' weights into ws: per layer, [OUT][IN/2] half2 K-pairs.
// Offsets (u32): fm 0(64), c1 64(128), p1 192(96), c2 288(48), p2 336(16), c3 352(8).
__global__ void pack_weights(const float* __restrict__ W_fm, const float* __restrict__ W1,
                             const float* __restrict__ Wp1, const float* __restrict__ W2,
                             const float* __restrict__ Wp2, const float* __restrict__ W3,
                             uint32_t* __restrict__ ws) {
    int i = blockIdx.x * blockDim.x + threadIdx.x;
    const float* W; int j, kp, stride, base;
    if      (i < 64)  { int t = i;       j = t >> 2; kp = t & 3; W = W_fm; stride = 16; base = 0; }
    else if (i < 192) { int t = i - 64;  j = t >> 3; kp = t & 7; W = W1;  stride = 16; base = 64; }
    else if (i < 288) { int t = i - 192; j = t >> 3; kp = t & 7; W = Wp1; stride = 12; base = 192; }
    else if (i < 336) { int t = i - 288; j = t / 6;  kp = t % 6; W = W2;  stride = 8;  base = 288; }
    else if (i < 352) { int t = i - 336; j = t >> 2; kp = t & 3; W = Wp2; stride = 4;  base = 336; }
    else if (i < 360) { int t = i - 352; j = t >> 1; kp = t & 1; W = W3;  stride = 4;  base = 352; }
    else return;
    ws[i] = __builtin_bit_cast(uint32_t,
        __floats2half2_rn(W[(2 * kp) * stride + j], W[(2 * kp + 1) * stride + j]));
}

__global__ __launch_bounds__(THREADS) void qcnn_fused(
        const float* __restrict__ inputs,
        const uint32_t* __restrict__ wq,
        const float* __restrict__ b_fm, const float* __restrict__ b1,
        const float* __restrict__ bp1,  const float* __restrict__ b2,
        const float* __restrict__ bp2,  const float* __restrict__ b3,
        const float* __restrict__ protos,
        const float* __restrict__ Wh,   const float* __restrict__ bh,
        float* __restrict__ out, int B) {
    const int tid = blockIdx.x * THREADS + threadIdx.x;
    if (tid >= B) return;

    float xa[16], xb[16];

    const float4* in4 = reinterpret_cast<const float4*>(inputs) + (size_t)tid * 2;
    float4 v0 = in4[0], v1 = in4[1];
    xa[0] = v0.x; xa[1] = v0.y; xa[2] = v0.z; xa[3] = v0.w;
    xa[4] = v1.x; xa[5] = v1.y; xa[6] = v1.z; xa[7] = v1.w;

    dense_h<8, 16>(xa, xb, wq + 0,   b_fm);  // feature_map
    dense_h<16, 16>(xb, xa, wq + 64,  b1);   // conv1
    dense_h<16, 12>(xa, xb, wq + 192, bp1);  // pool1
    dense_h<12, 8>(xb, xa, wq + 288, b2);    // conv2
    dense_h<8, 4>(xa, xb, wq + 336, bp2);    // pool2
    dense_h<4, 4>(xb, xa, wq + 352, b3);     // conv3 -> xa[0..3]

    // head x-part + RBF features vs 10 prototypes (GAMMA = 1) — f32, as R7
    v2f ha = { bh[0], 0.0f };
    ha += (v2f){ xa[0], xa[1] } * (v2f){ Wh[0], Wh[1] };
    ha += (v2f){ xa[2], xa[3] } * (v2f){ Wh[2], Wh[3] };
    float acc = ha.x + ha.y;

#pragma unroll
    for (int j = 0; j < 10; j += 2) {
        v2f d2 = { 0.0f, 0.0f };
#pragma unroll
        for (int k = 0; k < 4; ++k) {
            v2f p = { protos[j * 4 + k], protos[(j + 1) * 4 + k] };
            v2f d = (v2f){ xa[k], xa[k] } - p;
            d2 += d * d;
        }
        v2f d2s = d2 * -1.4426950408889634f;        // -log2e
        float kf0 = __builtin_amdgcn_exp2f(d2s.x);  // exp(-d2)
        float kf1 = __builtin_amdgcn_exp2f(d2s.y);
        acc = fmaf(kf0, Wh[4 + j], acc);
        acc = fmaf(kf1, Wh[5 + j], acc);
    }
    // sigmoid
    float e = __builtin_amdgcn_exp2f(acc * -1.4426950408889634f);
    out[tid] = __builtin_amdgcn_rcpf(1.0f + e);
}

extern "C" void kernel_launch(void* const* d_in, const int* in_sizes, int n_in,
                              void* d_out, int out_size, void* d_ws, size_t ws_size,
                              hipStream_t stream) {
    const float* inputs = (const float*)d_in[0];
    float* out = (float*)d_out;
    const int B = in_sizes[0] / 8;

    uint32_t* wq = (uint32_t*)d_ws;
    pack_weights<<<1, 512, 0, stream>>>(
        (const float*)d_in[1],  (const float*)d_in[3],  (const float*)d_in[5],
        (const float*)d_in[7],  (const float*)d_in[9],  (const float*)d_in[11],
        wq);

    const int blocks = (B + THREADS - 1) / THREADS;
    qcnn_fused<<<blocks, THREADS, 0, stream>>>(
        inputs, wq,
        (const float*)d_in[2],  (const float*)d_in[4],
        (const float*)d_in[6],  (const float*)d_in[8],
        (const float*)d_in[10], (const float*)d_in[12],
        (const float*)d_in[13],
        (const float*)d_in[14], (const float*)d_in[15],
        out, B);
}